// Round 7
// baseline (2209.336 us; speedup 1.0000x reference)
//
#include <hip/hip_runtime.h>
#include <cstddef>
#include <cstdint>

#define PI_F 3.14159265358979323846f

typedef __attribute__((ext_vector_type(8))) short short8;   // 8 bf16 = 4 VGPRs
typedef __attribute__((ext_vector_type(4))) float floatx4;  // MFMA acc

__device__ __forceinline__ short f2bf(float f) {
    union { float f; unsigned u; } v; v.f = f;
    unsigned r = v.u + 0x7FFFu + ((v.u >> 16) & 1u);   // RNE
    return (short)(r >> 16);
}

// ---------------------------------------------------------------------------
// Weight transpose+convert: Abf[m][k'] = bf16(A[m][c*K2 + tap]), k' = tap*Cp+c
// ---------------------------------------------------------------------------
__global__ __launch_bounds__(256) void wtrans_kernel(
    const float* __restrict__ A, short* __restrict__ Abf,
    int M, int Mpad, int K2, int C, int Cp, int Kp, int Korig)
{
    int idx = blockIdx.x * 256 + threadIdx.x;
    if (idx >= Mpad * Kp) return;
    int m = idx / Kp;
    int k = idx - m * Kp;
    int tap = (unsigned)k / (unsigned)Cp;
    int c   = k - tap * Cp;
    float v = 0.f;
    if (m < M && tap < K2 && c < C) v = A[(size_t)m * Korig + c * K2 + tap];
    Abf[idx] = f2bf(v);
}

__global__ __launch_bounds__(256) void zero_kernel(float* __restrict__ p, int n)
{
    int i = blockIdx.x * 256 + threadIdx.x;
    if (i < n) p[i] = 0.f;
}

// ---------------------------------------------------------------------------
// Fused spherical-conv GEMM, bf16 MFMA, channel-innermost K, SW-pipelined.
// Flat 1-D grid with XCD swizzle: logical = (pid%8)*(total/8) + pid/8,
// m-inner / n-major -> each XCD gets a contiguous n-range (L2 row reuse).
// Pipeline: corner loads for tile t+1 issued into registers right after the
// barrier, before tile t's MFMAs -> loads in flight across MFMA+ds_read+bar.
// Epilogue: bias add + per-channel sum/sumsq reduced over 16 lanes
// (shfl_xor) and atomicAdd'ed into accum[] -> BN stats pass eliminated.
// ---------------------------------------------------------------------------
#define BMT 64
#define BNT 64
#define BKT 32
#define LDK 40

__global__ __launch_bounds__(256) void sconv_mfma_kernel(
    const short* __restrict__ Abf, const float* __restrict__ bias,
    const float* __restrict__ src1, const float* __restrict__ src2,
    float* __restrict__ accum,
    int C1, int Ctot, int Cp, int H, int W, int up1,
    int K2, int ksz, int stride, int lWo, int lHo, float delta,
    float* __restrict__ Y, int M, int Kp, int N, int lgM)
{
    __shared__ short Bs[BNT][LDK];
    __shared__ float4 tab[64];          // max nHo*K2 = 49 over all layers

    const int tid = threadIdx.x;
    // ---- XCD swizzle (total % 8 == 0 for all layers) ----
    const int total = gridDim.x;
    const int pid = blockIdx.x;
    const int logical = (pid & 7) * (total >> 3) + (pid >> 3);
    const int m0 = (logical & ((1 << lgM) - 1)) * BMT;
    const int n0 = (logical >> lgM) * BNT;

    const int Wo  = 1 << lWo;
    const int Ho  = 1 << lHo;
    const int HW  = 1 << (lWo + lHo);

    // ---- per-block grid table: (hoLocal, tap) -> {fr, dcol, r0i, r1i} ----
    const int nHo  = (lWo >= 6) ? 1 : (BNT >> lWo);
    const int nEnt = nHo * K2;
    const int hoBase = (n0 >> lWo) & (Ho - 1);
    if (tid < nEnt) {
        int hoL = tid / K2;
        int i   = tid - hoL * K2;
        int ho_g = hoBase + hoL;
        int jy = i / ksz, jx = i - jy * ksz;
        float halfk = (ksz - 1) * 0.5f;
        float yy = tanf(delta / (float)ksz * ((float)jy - halfk));
        float xx = tanf(delta / (float)ksz * ((float)jx - halfk));
        float rho = sqrtf(xx * xx + yy * yy);
        float rho_s = (rho == 0.f) ? 1.f : rho;
        float nu = atanf(rho);
        float lat0 = PI_F * 0.5f - ((float)(ho_g * stride) + 0.5f) * (PI_F / (float)H);
        float sl = sinf(lat0), cl = cosf(lat0);
        float sn = sinf(nu),  cn = cosf(nu);
        float arg = cn * sl + (yy / rho_s) * sn * cl;
        arg = fminf(1.f, fmaxf(-1.f, arg));
        float lat = asinf(arg);
        float dlon = atan2f(xx * sn, rho * cl * cn - yy * sl * sn);
        float row = (PI_F * 0.5f - lat) / PI_F * (float)H - 0.5f;
        float dcol = dlon / (2.f * PI_F) * (float)W;
        float r0f = floorf(row);
        float fr = row - r0f;
        int r0 = (int)r0f;
        int r0i = min(max(r0, 0), H - 1);
        int r1i = min(max(r0 + 1, 0), H - 1);
        tab[tid] = make_float4(fr, dcol, __int_as_float(r0i), __int_as_float(r1i));
    }

    // ---- B staging geometry (lane nn = coalesced wo) ----
    const int nn    = tid & 63;
    const int kslot = tid >> 6;         // wave-uniform
    const int n_s  = n0 + nn;
    const int wo_s = n_s & (Wo - 1);
    const int hoL_s = nn >> lWo;
    const int b_s  = n_s >> (lWo + lHo);   // block-uniform (HW multiple of 64)
    const int tabBase = hoL_s * K2;
    const float wo_px = (float)(wo_s * stride);
    const int Hs = H >> up1, Ws = W >> up1;
    const int plane1 = Hs * Ws;
    const int plane2 = H * W;
    const unsigned boff1 = (unsigned)(b_s * C1 * plane1);
    const unsigned boff2 = (unsigned)(b_s * (Ctot - C1) * plane2);

    // ---- (tap, cb) iteration state: chunk = one tap, 8 channels ----
    const bool smallC = (Cp < 32);      // layer 1 only (Cp=8)
    int tap = smallC ? kslot : 0;
    int cb  = smallC ? 0 : kslot * 8;
    const int dtap = smallC ? (32 / Cp) : 0;

    // ---- wave/lane decomposition for MFMA ----
    const int wave = tid >> 6;
    const int wm   = (wave & 1) * 32;
    const int wn   = (wave >> 1) * 32;
    const int lane = tid & 63;
    const int l16  = lane & 15;
    const int quad = lane >> 4;

    const short* pA0 = Abf + (size_t)(m0 + wm + l16) * Kp + quad * 8;
    const short* pA1 = pA0 + (size_t)16 * Kp;

    floatx4 acc[2][2];
#pragma unroll
    for (int i = 0; i < 2; i++)
#pragma unroll
        for (int j = 0; j < 2; j++)
            acc[i][j] = (floatx4){0.f, 0.f, 0.f, 0.f};

    // ---- pipeline registers: corners + bilinear weights for one tile ----
    float4 cor[8];
    float4 wv;
    auto issueLoads = [&](int tp, int cbb) {
        const int tapc = min(tp, K2 - 1);       // clamp for L1 pad region
        const float4 e = tab[tabBase + tapc];
        const float fr = e.x;
        const float col = wo_px + e.y;
        const int r0i = __float_as_int(e.z);
        const int r1i = __float_as_int(e.w);
        const float cf = floorf(col);
        const float fc = col - cf;
        const int c0 = ((int)cf) & (W - 1);
        const int c1 = (c0 + 1) & (W - 1);
        wv.x = (1.f - fr) * (1.f - fc);
        wv.y = (1.f - fr) * fc;
        wv.z = fr * (1.f - fc);
        wv.w = fr * fc;
        const float* src; unsigned i00, i01, i10, i11, plane;
        if (cbb < C1) {                  // wave-uniform branch
            const int ra = (r0i >> up1) * Ws, rb = (r1i >> up1) * Ws;
            const int ca = c0 >> up1, cx = c1 >> up1;
            const unsigned base = boff1 + (unsigned)cbb * plane1;
            i00 = base + ra + ca; i01 = base + ra + cx;
            i10 = base + rb + ca; i11 = base + rb + cx;
            plane = plane1; src = src1;
        } else {
            const int ra = r0i * W, rb = r1i * W;
            const unsigned base = boff2 + (unsigned)(cbb - C1) * plane2;
            i00 = base + ra + c0; i01 = base + ra + c1;
            i10 = base + rb + c0; i11 = base + rb + c1;
            plane = plane2; src = src2;
        }
#pragma unroll
        for (int j = 0; j < 8; j++) {
            if (cbb + j < Ctot)          // guard BEFORE loads (L1: src2 null)
                cor[j] = make_float4(src[i00], src[i01], src[i10], src[i11]);
            else
                cor[j] = make_float4(0.f, 0.f, 0.f, 0.f);
            i00 += plane; i01 += plane; i10 += plane; i11 += plane;
        }
    };

    __syncthreads();   // table ready
    issueLoads(tap, cb);               // prefetch tile 0

    const int T = Kp / BKT;
    for (int t = 0; t < T; t++) {
        // ---- combine current tile's corners -> bf16 -> LDS ----
        short t8[8];
#pragma unroll
        for (int j = 0; j < 8; j++) {
            float v = wv.x * cor[j].x + wv.y * cor[j].y
                    + wv.z * cor[j].z + wv.w * cor[j].w;
            t8[j] = f2bf(v);
        }
        *(short8*)&Bs[nn][kslot * 8] = *(short8*)&t8[0];
        __syncthreads();

        // ---- advance state + prefetch next tile (loads fly over MFMA) ----
        if (smallC) { tap += dtap; }
        else { cb += 32; if (cb >= Cp) { cb -= Cp; tap++; } }
        if (t + 1 < T) issueLoads(tap, cb);

        const int k0 = t * BKT;
        const short8 af0 = *(const short8*)(pA0 + k0);
        const short8 af1 = *(const short8*)(pA1 + k0);
        const short8 b0 = *(const short8*)&Bs[wn + l16][quad * 8];
        const short8 b1 = *(const short8*)&Bs[wn + 16 + l16][quad * 8];
        acc[0][0] = __builtin_amdgcn_mfma_f32_16x16x32_bf16(af0, b0, acc[0][0], 0, 0, 0);
        acc[0][1] = __builtin_amdgcn_mfma_f32_16x16x32_bf16(af0, b1, acc[0][1], 0, 0, 0);
        acc[1][0] = __builtin_amdgcn_mfma_f32_16x16x32_bf16(af1, b0, acc[1][0], 0, 0, 0);
        acc[1][1] = __builtin_amdgcn_mfma_f32_16x16x32_bf16(af1, b1, acc[1][1], 0, 0, 0);
        __syncthreads();
    }

    // ---- epilogue: store + fused BN partial stats ----
    // C/D layout col=lane&15, row=quad*4+reg. Per (i,rr): sum over j + 16
    // lanes (shfl_xor) -> one atomicAdd pair per 16-lane group.
#pragma unroll
    for (int i = 0; i < 2; i++) {
#pragma unroll
        for (int rr = 0; rr < 4; rr++) {
            const int m = m0 + wm + i * 16 + quad * 4 + rr;
            const bool mv = (m < M);
            const float bv = mv ? bias[m] : 0.f;
            float s = 0.f, q = 0.f;
#pragma unroll
            for (int j = 0; j < 2; j++) {
                const int n = n0 + wn + j * 16 + l16;
                const float v = acc[i][j][rr] + bv;
                s += v; q += v * v;
                if (mv) {
                    const int wo = n & (Wo - 1);
                    const int r  = n >> lWo;
                    const int ho = r & (Ho - 1);
                    const int b_ = r >> lHo;
                    Y[((size_t)b_ * M + m) * HW + (ho << lWo) + wo] = v;
                }
            }
#pragma unroll
            for (int mask = 1; mask < 16; mask <<= 1) {
                s += __shfl_xor(s, mask);
                q += __shfl_xor(q, mask);
            }
            if (mv && l16 == 0) {
                atomicAdd(&accum[m * 2], s);
                atomicAdd(&accum[m * 2 + 1], q);
            }
        }
    }
}

// ---------------------------------------------------------------------------
// BN finalize + normalize + ReLU (stats read from fused accumulators).
// ---------------------------------------------------------------------------
__global__ __launch_bounds__(256) void bn_apply_kernel(
    float* __restrict__ Y, const float* __restrict__ accum,
    const float* __restrict__ g, const float* __restrict__ bb,
    int Co, int HW, int Nt, int total)
{
    int idx = blockIdx.x * 256 + threadIdx.x;
    if (idx >= total) return;
    int c = (idx / HW) % Co;           // uniform within block (256 | HW)
    float mean = accum[c * 2] / (float)Nt;
    float var = accum[c * 2 + 1] / (float)Nt - mean * mean;
    var = fmaxf(var, 0.f);
    float sc = g[c] / sqrtf(var + 1e-5f);
    float sf = bb[c] - mean * sc;
    float v = Y[idx] * sc + sf;
    Y[idx] = v > 0.f ? v : 0.f;
}

// ---------------------------------------------------------------------------
// Host orchestration. Workspace ~35 MB: accum 16KB + activations 29.4MB +
// Abf 5.1MB. Scratch Q reuse by lifetime: x1=Q (L1-2), x3=Q (L3-4),
// x4=Q (L5-6), x41=Q+512K (L6-7), x5=Q+1M (L7-8).
// ---------------------------------------------------------------------------
extern "C" void kernel_launch(void* const* d_in, const int* in_sizes, int n_in,
                              void* d_out, int out_size, void* d_ws, size_t ws_size,
                              hipStream_t stream)
{
    const int B = 4;
    char* ws = (char*)d_ws;
    size_t off = 0;
    auto allocb = [&](size_t bytes) -> void* {
        void* p = ws + off;
        off = (off + bytes + 255) & ~(size_t)255;
        return p;
    };

    float* accumAll = (float*)allocb(8 * 512 * sizeof(float));  // 8 layers x 256ch x {s,q}
    float* x2  = (float*)allocb((size_t)B * 64  * 64 * 128 * 4);
    float* x31 = (float*)allocb((size_t)B * 128 * 32 * 64 * 4);
    float* Q   = (float*)allocb((size_t)B * 32  * 128 * 256 * 4);
    float* x1  = Q;
    float* x3  = Q;
    float* x4  = Q;
    float* x41 = Q + (size_t)B * 256 * 16 * 32;
    float* x5  = Q + 2 * (size_t)B * 256 * 16 * 32;

    //                      1     2     3    31     4    41     5     6
    static const int kH[8]  = {256, 128,  64,  32,  32,  16,  32,  64};
    static const int kW[8]  = {512, 256, 128,  64,  64,  32,  64, 128};
    static const int kK[8]  = {  7,   5,   5,   3,   3,   3,   3,   3};
    static const int kSt[8] = {  2,   2,   2,   1,   2,   1,   1,   1};
    static const int kC[8]  = {  6,  32,  64, 128, 128, 256, 384, 320};
    static const int kM[8]  = { 32,  64, 128, 128, 256, 256, 256, 128};

    int Cp_[8], Kp_[8], Mpad_[8];
    short* Abf[8];
    for (int i = 0; i < 8; i++) {
        int K2 = kK[i] * kK[i];
        int Cp = (kC[i] < 8) ? 8 : kC[i];
        int Kp = (K2 * Cp + 31) & ~31;
        int Mpad = (kM[i] + 63) & ~63;
        Cp_[i] = Cp; Kp_[i] = Kp; Mpad_[i] = Mpad;
        Abf[i] = (short*)allocb((size_t)Mpad * Kp * sizeof(short));
    }
    (void)ws_size; (void)in_sizes; (void)n_in; (void)out_size;

    struct LCfg { const float *s1, *s2; int C1, up; float delta; int widx; float* Y; };
    const float* input = (const float*)d_in[0];
    LCfg L[8] = {
        { input, nullptr,   6, 0, PI_F / 32.f,  1, x1  },
        { x1,    nullptr,  32, 0, PI_F / 16.f,  5, x2  },
        { x2,    nullptr,  64, 0, PI_F / 4.f,   9, x3  },
        { x3,    nullptr, 128, 0, PI_F / 4.f,  13, x31 },
        { x31,   nullptr, 128, 0, PI_F / 2.f,  17, x4  },
        { x4,    nullptr, 256, 0, PI_F / 2.f,  21, x41 },
        { x41,   x31,     256, 1, PI_F / 4.f,  25, x5  },
        { x5,    x2,      256, 1, PI_F / 8.f,  29, (float*)d_out },
    };

    zero_kernel<<<dim3(16), dim3(256), 0, stream>>>(accumAll, 8 * 512);

    for (int i = 0; i < 8; i++) {
        const LCfg& c = L[i];
        int H = kH[i], W = kW[i], k = kK[i], st = kSt[i];
        int Ho = H / st, Wo = W / st;
        int K2 = k * k;
        int C  = kC[i], M = kM[i];
        int HW = Ho * Wo;
        int N  = B * HW;
        int lWo = __builtin_ctz(Wo), lHo = __builtin_ctz(Ho);
        const float* Wt   = (const float*)d_in[c.widx];
        const float* bias = (const float*)d_in[c.widx + 1];
        const float* gam  = (const float*)d_in[c.widx + 2];
        const float* bet  = (const float*)d_in[c.widx + 3];
        float* accum = accumAll + i * 512;

        int tn = Mpad_[i] * Kp_[i];
        wtrans_kernel<<<dim3((tn + 255) / 256), dim3(256), 0, stream>>>(
            Wt, Abf[i], M, Mpad_[i], K2, C, Cp_[i], Kp_[i], C * K2);

        int nBlkM = Mpad_[i] / BMT;
        int totalBlk = (N / BNT) * nBlkM;          // % 8 == 0 for all layers
        int lgM = __builtin_ctz(nBlkM);
        sconv_mfma_kernel<<<dim3(totalBlk), dim3(256), 0, stream>>>(
            Abf[i], bias, c.s1, c.s2, accum, c.C1, C, Cp_[i], H, W, c.up,
            K2, k, st, lWo, lHo, c.delta,
            c.Y, M, Kp_[i], N, lgM);

        int total = B * M * HW;
        bn_apply_kernel<<<dim3(total / 256), dim3(256), 0, stream>>>(
            c.Y, accum, gam, bet, M, HW, N, total);
    }
}

// Round 8
// 2207.732 us; speedup vs baseline: 1.0007x; 1.0007x over previous
//
#include <hip/hip_runtime.h>
#include <cstddef>
#include <cstdint>

#define PI_F 3.14159265358979323846f

typedef __attribute__((ext_vector_type(8))) short short8;   // 8 bf16 = 4 VGPRs
typedef __attribute__((ext_vector_type(4))) float floatx4;  // MFMA acc

__device__ __forceinline__ short f2bf(float f) {
    union { float f; unsigned u; } v; v.f = f;
    unsigned r = v.u + 0x7FFFu + ((v.u >> 16) & 1u);   // RNE
    return (short)(r >> 16);
}

// ---------------------------------------------------------------------------
// Weight transpose+convert: Abf[m][k'] = bf16(A[m][c*K2 + tap]), k' = tap*Cp+c
// ---------------------------------------------------------------------------
__global__ __launch_bounds__(256) void wtrans_kernel(
    const float* __restrict__ A, short* __restrict__ Abf,
    int M, int Mpad, int K2, int C, int Cp, int Kp, int Korig)
{
    int idx = blockIdx.x * 256 + threadIdx.x;
    if (idx >= Mpad * Kp) return;
    int m = idx / Kp;
    int k = idx - m * Kp;
    int tap = (unsigned)k / (unsigned)Cp;
    int c   = k - tap * Cp;
    float v = 0.f;
    if (m < M && tap < K2 && c < C) v = A[(size_t)m * Korig + c * K2 + tap];
    Abf[idx] = f2bf(v);
}

__global__ __launch_bounds__(256) void zero_kernel(float* __restrict__ p, int n)
{
    int i = blockIdx.x * 256 + threadIdx.x;
    if (i < n) p[i] = 0.f;
}

// ---------------------------------------------------------------------------
// Fused spherical-conv GEMM, bf16 MFMA, channel-innermost K, SW-pipelined.
// __launch_bounds__(256, 2): 2 blocks/CU target -> VGPR budget 256 so the
// 8x float4 corner prefetch buffer REGISTERIZES (round 7: default budget
// chose 44 VGPRs and spilled the pipeline to scratch -> 2x regression).
// Flat 1-D grid with XCD swizzle: logical = (pid%8)*(total/8) + pid/8,
// m-inner / n-major -> each XCD gets a contiguous n-range (L2 row reuse;
// round-7 counters: FETCH_SIZE 488MB -> 6.6MB).
// Pipeline: corner loads for tile t+1 issued right after the barrier,
// before tile t's MFMAs -> loads in flight across MFMA+ds_read+barrier.
// Epilogue: bias add + per-channel sum/sumsq (shfl_xor over 16 lanes) +
// atomicAdd into accum[] -> separate BN stats pass eliminated.
// ---------------------------------------------------------------------------
#define BMT 64
#define BNT 64
#define BKT 32
#define LDK 40

__global__ __launch_bounds__(256, 2) void sconv_mfma_kernel(
    const short* __restrict__ Abf, const float* __restrict__ bias,
    const float* __restrict__ src1, const float* __restrict__ src2,
    float* __restrict__ accum,
    int C1, int Ctot, int Cp, int H, int W, int up1,
    int K2, int ksz, int stride, int lWo, int lHo, float delta,
    float* __restrict__ Y, int M, int Kp, int N, int lgM)
{
    __shared__ short Bs[BNT][LDK];
    __shared__ float4 tab[64];          // max nHo*K2 = 49 over all layers

    const int tid = threadIdx.x;
    // ---- XCD swizzle (total % 8 == 0 for all layers) ----
    const int total = gridDim.x;
    const int pid = blockIdx.x;
    const int logical = (pid & 7) * (total >> 3) + (pid >> 3);
    const int m0 = (logical & ((1 << lgM) - 1)) * BMT;
    const int n0 = (logical >> lgM) * BNT;

    const int Wo  = 1 << lWo;
    const int Ho  = 1 << lHo;
    const int HW  = 1 << (lWo + lHo);

    // ---- per-block grid table: (hoLocal, tap) -> {fr, dcol, r0i, r1i} ----
    const int nHo  = (lWo >= 6) ? 1 : (BNT >> lWo);
    const int nEnt = nHo * K2;
    const int hoBase = (n0 >> lWo) & (Ho - 1);
    if (tid < nEnt) {
        int hoL = tid / K2;
        int i   = tid - hoL * K2;
        int ho_g = hoBase + hoL;
        int jy = i / ksz, jx = i - jy * ksz;
        float halfk = (ksz - 1) * 0.5f;
        float yy = tanf(delta / (float)ksz * ((float)jy - halfk));
        float xx = tanf(delta / (float)ksz * ((float)jx - halfk));
        float rho = sqrtf(xx * xx + yy * yy);
        float rho_s = (rho == 0.f) ? 1.f : rho;
        float nu = atanf(rho);
        float lat0 = PI_F * 0.5f - ((float)(ho_g * stride) + 0.5f) * (PI_F / (float)H);
        float sl = sinf(lat0), cl = cosf(lat0);
        float sn = sinf(nu),  cn = cosf(nu);
        float arg = cn * sl + (yy / rho_s) * sn * cl;
        arg = fminf(1.f, fmaxf(-1.f, arg));
        float lat = asinf(arg);
        float dlon = atan2f(xx * sn, rho * cl * cn - yy * sl * sn);
        float row = (PI_F * 0.5f - lat) / PI_F * (float)H - 0.5f;
        float dcol = dlon / (2.f * PI_F) * (float)W;
        float r0f = floorf(row);
        float fr = row - r0f;
        int r0 = (int)r0f;
        int r0i = min(max(r0, 0), H - 1);
        int r1i = min(max(r0 + 1, 0), H - 1);
        tab[tid] = make_float4(fr, dcol, __int_as_float(r0i), __int_as_float(r1i));
    }

    // ---- B staging geometry (lane nn = coalesced wo) ----
    const int nn    = tid & 63;
    const int kslot = tid >> 6;         // wave-uniform
    const int n_s  = n0 + nn;
    const int wo_s = n_s & (Wo - 1);
    const int hoL_s = nn >> lWo;
    const int b_s  = n_s >> (lWo + lHo);   // block-uniform (HW multiple of 64)
    const int tabBase = hoL_s * K2;
    const float wo_px = (float)(wo_s * stride);
    const int Hs = H >> up1, Ws = W >> up1;
    const int plane1 = Hs * Ws;
    const int plane2 = H * W;
    const unsigned boff1 = (unsigned)(b_s * C1 * plane1);
    const unsigned boff2 = (unsigned)(b_s * (Ctot - C1) * plane2);

    // ---- (tap, cb) iteration state: chunk = one tap, 8 channels ----
    const bool smallC = (Cp < 32);      // layer 1 only (Cp=8)
    int tap = smallC ? kslot : 0;
    int cb  = smallC ? 0 : kslot * 8;
    const int dtap = smallC ? (32 / Cp) : 0;

    // ---- wave/lane decomposition for MFMA ----
    const int wave = tid >> 6;
    const int wm   = (wave & 1) * 32;
    const int wn   = (wave >> 1) * 32;
    const int lane = tid & 63;
    const int l16  = lane & 15;
    const int quad = lane >> 4;

    const short* pA0 = Abf + (size_t)(m0 + wm + l16) * Kp + quad * 8;
    const short* pA1 = pA0 + (size_t)16 * Kp;

    floatx4 acc[2][2];
#pragma unroll
    for (int i = 0; i < 2; i++)
#pragma unroll
        for (int j = 0; j < 2; j++)
            acc[i][j] = (floatx4){0.f, 0.f, 0.f, 0.f};

    // ---- pipeline registers: corners + bilinear weights for one tile ----
    float4 cor[8];
    float4 wv;
    auto issueLoads = [&](int tp, int cbb) {
        const int tapc = min(tp, K2 - 1);       // clamp for L1 pad region
        const float4 e = tab[tabBase + tapc];
        const float fr = e.x;
        const float col = wo_px + e.y;
        const int r0i = __float_as_int(e.z);
        const int r1i = __float_as_int(e.w);
        const float cf = floorf(col);
        const float fc = col - cf;
        const int c0 = ((int)cf) & (W - 1);
        const int c1 = (c0 + 1) & (W - 1);
        wv.x = (1.f - fr) * (1.f - fc);
        wv.y = (1.f - fr) * fc;
        wv.z = fr * (1.f - fc);
        wv.w = fr * fc;
        const float* src; unsigned i00, i01, i10, i11, plane;
        if (cbb < C1) {                  // wave-uniform branch
            const int ra = (r0i >> up1) * Ws, rb = (r1i >> up1) * Ws;
            const int ca = c0 >> up1, cx = c1 >> up1;
            const unsigned base = boff1 + (unsigned)cbb * plane1;
            i00 = base + ra + ca; i01 = base + ra + cx;
            i10 = base + rb + ca; i11 = base + rb + cx;
            plane = plane1; src = src1;
        } else {
            const int ra = r0i * W, rb = r1i * W;
            const unsigned base = boff2 + (unsigned)(cbb - C1) * plane2;
            i00 = base + ra + c0; i01 = base + ra + c1;
            i10 = base + rb + c0; i11 = base + rb + c1;
            plane = plane2; src = src2;
        }
#pragma unroll
        for (int j = 0; j < 8; j++) {
            if (cbb + j < Ctot)          // guard BEFORE loads (L1: src2 null)
                cor[j] = make_float4(src[i00], src[i01], src[i10], src[i11]);
            else
                cor[j] = make_float4(0.f, 0.f, 0.f, 0.f);
            i00 += plane; i01 += plane; i10 += plane; i11 += plane;
        }
    };

    __syncthreads();   // table ready
    issueLoads(tap, cb);               // prefetch tile 0

    const int T = Kp / BKT;
    for (int t = 0; t < T; t++) {
        // ---- combine current tile's corners -> bf16 -> LDS ----
        short t8[8];
#pragma unroll
        for (int j = 0; j < 8; j++) {
            float v = wv.x * cor[j].x + wv.y * cor[j].y
                    + wv.z * cor[j].z + wv.w * cor[j].w;
            t8[j] = f2bf(v);
        }
        *(short8*)&Bs[nn][kslot * 8] = *(short8*)&t8[0];
        __syncthreads();

        // ---- advance state + prefetch next tile (loads fly over MFMA) ----
        if (smallC) { tap += dtap; }
        else { cb += 32; if (cb >= Cp) { cb -= Cp; tap++; } }
        if (t + 1 < T) issueLoads(tap, cb);

        const int k0 = t * BKT;
        const short8 af0 = *(const short8*)(pA0 + k0);
        const short8 af1 = *(const short8*)(pA1 + k0);
        const short8 b0 = *(const short8*)&Bs[wn + l16][quad * 8];
        const short8 b1 = *(const short8*)&Bs[wn + 16 + l16][quad * 8];
        acc[0][0] = __builtin_amdgcn_mfma_f32_16x16x32_bf16(af0, b0, acc[0][0], 0, 0, 0);
        acc[0][1] = __builtin_amdgcn_mfma_f32_16x16x32_bf16(af0, b1, acc[0][1], 0, 0, 0);
        acc[1][0] = __builtin_amdgcn_mfma_f32_16x16x32_bf16(af1, b0, acc[1][0], 0, 0, 0);
        acc[1][1] = __builtin_amdgcn_mfma_f32_16x16x32_bf16(af1, b1, acc[1][1], 0, 0, 0);
        __syncthreads();
    }

    // ---- epilogue: store + fused BN partial stats ----
#pragma unroll
    for (int i = 0; i < 2; i++) {
#pragma unroll
        for (int rr = 0; rr < 4; rr++) {
            const int m = m0 + wm + i * 16 + quad * 4 + rr;
            const bool mv = (m < M);
            const float bv = mv ? bias[m] : 0.f;
            float s = 0.f, q = 0.f;
#pragma unroll
            for (int j = 0; j < 2; j++) {
                const int n = n0 + wn + j * 16 + l16;
                const float v = acc[i][j][rr] + bv;
                s += v; q += v * v;
                if (mv) {
                    const int wo = n & (Wo - 1);
                    const int r  = n >> lWo;
                    const int ho = r & (Ho - 1);
                    const int b_ = r >> lHo;
                    Y[((size_t)b_ * M + m) * HW + (ho << lWo) + wo] = v;
                }
            }
#pragma unroll
            for (int mask = 1; mask < 16; mask <<= 1) {
                s += __shfl_xor(s, mask);
                q += __shfl_xor(q, mask);
            }
            if (mv && l16 == 0) {
                atomicAdd(&accum[m * 2], s);
                atomicAdd(&accum[m * 2 + 1], q);
            }
        }
    }
}

// ---------------------------------------------------------------------------
// BN finalize + normalize + ReLU (stats read from fused accumulators).
// ---------------------------------------------------------------------------
__global__ __launch_bounds__(256) void bn_apply_kernel(
    float* __restrict__ Y, const float* __restrict__ accum,
    const float* __restrict__ g, const float* __restrict__ bb,
    int Co, int HW, int Nt, int total)
{
    int idx = blockIdx.x * 256 + threadIdx.x;
    if (idx >= total) return;
    int c = (idx / HW) % Co;           // uniform within block (256 | HW)
    float mean = accum[c * 2] / (float)Nt;
    float var = accum[c * 2 + 1] / (float)Nt - mean * mean;
    var = fmaxf(var, 0.f);
    float sc = g[c] / sqrtf(var + 1e-5f);
    float sf = bb[c] - mean * sc;
    float v = Y[idx] * sc + sf;
    Y[idx] = v > 0.f ? v : 0.f;
}

// ---------------------------------------------------------------------------
// Host orchestration. Workspace ~35 MB: accum 16KB + activations 29.4MB +
// Abf 5.1MB. Scratch Q reuse by lifetime: x1=Q (L1-2), x3=Q (L3-4),
// x4=Q (L5-6), x41=Q+512K (L6-7), x5=Q+1M (L7-8).
// ---------------------------------------------------------------------------
extern "C" void kernel_launch(void* const* d_in, const int* in_sizes, int n_in,
                              void* d_out, int out_size, void* d_ws, size_t ws_size,
                              hipStream_t stream)
{
    const int B = 4;
    char* ws = (char*)d_ws;
    size_t off = 0;
    auto allocb = [&](size_t bytes) -> void* {
        void* p = ws + off;
        off = (off + bytes + 255) & ~(size_t)255;
        return p;
    };

    float* accumAll = (float*)allocb(8 * 512 * sizeof(float));  // 8 layers x 256ch x {s,q}
    float* x2  = (float*)allocb((size_t)B * 64  * 64 * 128 * 4);
    float* x31 = (float*)allocb((size_t)B * 128 * 32 * 64 * 4);
    float* Q   = (float*)allocb((size_t)B * 32  * 128 * 256 * 4);
    float* x1  = Q;
    float* x3  = Q;
    float* x4  = Q;
    float* x41 = Q + (size_t)B * 256 * 16 * 32;
    float* x5  = Q + 2 * (size_t)B * 256 * 16 * 32;

    //                      1     2     3    31     4    41     5     6
    static const int kH[8]  = {256, 128,  64,  32,  32,  16,  32,  64};
    static const int kW[8]  = {512, 256, 128,  64,  64,  32,  64, 128};
    static const int kK[8]  = {  7,   5,   5,   3,   3,   3,   3,   3};
    static const int kSt[8] = {  2,   2,   2,   1,   2,   1,   1,   1};
    static const int kC[8]  = {  6,  32,  64, 128, 128, 256, 384, 320};
    static const int kM[8]  = { 32,  64, 128, 128, 256, 256, 256, 128};

    int Cp_[8], Kp_[8], Mpad_[8];
    short* Abf[8];
    for (int i = 0; i < 8; i++) {
        int K2 = kK[i] * kK[i];
        int Cp = (kC[i] < 8) ? 8 : kC[i];
        int Kp = (K2 * Cp + 31) & ~31;
        int Mpad = (kM[i] + 63) & ~63;
        Cp_[i] = Cp; Kp_[i] = Kp; Mpad_[i] = Mpad;
        Abf[i] = (short*)allocb((size_t)Mpad * Kp * sizeof(short));
    }
    (void)ws_size; (void)in_sizes; (void)n_in; (void)out_size;

    struct LCfg { const float *s1, *s2; int C1, up; float delta; int widx; float* Y; };
    const float* input = (const float*)d_in[0];
    LCfg L[8] = {
        { input, nullptr,   6, 0, PI_F / 32.f,  1, x1  },
        { x1,    nullptr,  32, 0, PI_F / 16.f,  5, x2  },
        { x2,    nullptr,  64, 0, PI_F / 4.f,   9, x3  },
        { x3,    nullptr, 128, 0, PI_F / 4.f,  13, x31 },
        { x31,   nullptr, 128, 0, PI_F / 2.f,  17, x4  },
        { x4,    nullptr, 256, 0, PI_F / 2.f,  21, x41 },
        { x41,   x31,     256, 1, PI_F / 4.f,  25, x5  },
        { x5,    x2,      256, 1, PI_F / 8.f,  29, (float*)d_out },
    };

    zero_kernel<<<dim3(16), dim3(256), 0, stream>>>(accumAll, 8 * 512);

    for (int i = 0; i < 8; i++) {
        const LCfg& c = L[i];
        int H = kH[i], W = kW[i], k = kK[i], st = kSt[i];
        int Ho = H / st, Wo = W / st;
        int K2 = k * k;
        int C  = kC[i], M = kM[i];
        int HW = Ho * Wo;
        int N  = B * HW;
        int lWo = __builtin_ctz(Wo), lHo = __builtin_ctz(Ho);
        const float* Wt   = (const float*)d_in[c.widx];
        const float* bias = (const float*)d_in[c.widx + 1];
        const float* gam  = (const float*)d_in[c.widx + 2];
        const float* bet  = (const float*)d_in[c.widx + 3];
        float* accum = accumAll + i * 512;

        int tn = Mpad_[i] * Kp_[i];
        wtrans_kernel<<<dim3((tn + 255) / 256), dim3(256), 0, stream>>>(
            Wt, Abf[i], M, Mpad_[i], K2, C, Cp_[i], Kp_[i], C * K2);

        int nBlkM = Mpad_[i] / BMT;
        int totalBlk = (N / BNT) * nBlkM;          // % 8 == 0 for all layers
        int lgM = __builtin_ctz(nBlkM);
        sconv_mfma_kernel<<<dim3(totalBlk), dim3(256), 0, stream>>>(
            Abf[i], bias, c.s1, c.s2, accum, c.C1, C, Cp_[i], H, W, c.up,
            K2, k, st, lWo, lHo, c.delta,
            c.Y, M, Kp_[i], N, lgM);

        int total = B * M * HW;
        bn_apply_kernel<<<dim3(total / 256), dim3(256), 0, stream>>>(
            c.Y, accum, gam, bet, M, HW, N, total);
    }
}